// Round 5
// baseline (441.734 us; speedup 1.0000x reference)
//
#include <hip/hip_runtime.h>
#include <hip/hip_bf16.h>

typedef __attribute__((ext_vector_type(4))) float  f32x4;
typedef __attribute__((ext_vector_type(8))) short  short8;
typedef __attribute__((ext_vector_type(4))) short  short4v;

__device__ __forceinline__ unsigned short f32_to_bf16(float f) {
    union { float f; unsigned u; } v; v.f = f;
    unsigned r = v.u + 0x7FFFu + ((v.u >> 16) & 1u);   // RNE
    return (unsigned short)(r >> 16);
}
__device__ __forceinline__ float bf16_to_f32(unsigned short h) {
    union { unsigned u; float f; } v; v.u = ((unsigned)h) << 16; return v.f;
}
__device__ __forceinline__ void gload_lds16(const void* g, void* l) {
    __builtin_amdgcn_global_load_lds(
        (const __attribute__((address_space(1))) unsigned int*)g,
        (__attribute__((address_space(3))) unsigned int*)l,
        16, 0, 0);
}

// ---------------- transpose + fp32->bf16 convert ----------------
__global__ __launch_bounds__(256) void transpose_to_bf16(
    const float* __restrict__ src, unsigned short* __restrict__ dst,
    int R, int Cin, int Cpad) {
    __shared__ float tile[32][33];
    const int tx = threadIdx.x, ty = threadIdx.y;
    const int c0 = blockIdx.x * 32, r0 = blockIdx.y * 32;
#pragma unroll
    for (int i = 0; i < 4; ++i) {
        int r = r0 + ty + i * 8, c = c0 + tx;
        float v = 0.f;
        if (r < R && c < Cin) v = src[(size_t)r * Cin + c];
        tile[ty + i * 8][tx] = v;
    }
    __syncthreads();
#pragma unroll
    for (int i = 0; i < 4; ++i) {
        int c = c0 + ty + i * 8, r = r0 + tx;
        if (c < Cpad && r < R)
            dst[(size_t)c * R + r] = f32_to_bf16(tile[tx][ty + i * 8]);
    }
}

// ---------------- bias[c] = -sum_d mean[d] * Mt[c][d] ----------------
__global__ __launch_bounds__(256) void bias_kernel(
    const float* __restrict__ mean, const unsigned short* __restrict__ Mt,
    float* __restrict__ bias, int D) {
    const int c = blockIdx.x;
    const unsigned short* row = Mt + (size_t)c * D;
    float s = 0.f;
    for (int d0 = threadIdx.x * 8; d0 < D; d0 += 256 * 8) {
        short4v h0 = *(const short4v*)&row[d0];
        short4v h1 = *(const short4v*)&row[d0 + 4];
        f32x4  m0 = *(const f32x4*)&mean[d0];
        f32x4  m1 = *(const f32x4*)&mean[d0 + 4];
#pragma unroll
        for (int j = 0; j < 4; ++j) {
            s += bf16_to_f32((unsigned short)h0[j]) * m0[j];
            s += bf16_to_f32((unsigned short)h1[j]) * m1[j];
        }
    }
#pragma unroll
    for (int off = 32; off > 0; off >>= 1) s += __shfl_down(s, off);
    __shared__ float red[4];
    const int lane = threadIdx.x & 63, w = threadIdx.x >> 6;
    if (lane == 0) red[w] = s;
    __syncthreads();
    if (threadIdx.x == 0) bias[c] = -(red[0] + red[1] + red[2] + red[3]);
}

// ================= 128x128 tile, BK=64, 4 waves 2x2, acc[4][4] (m97/R2-proven) =================
#define BM 128
#define BN 128
#define BK 64

#define G1_BLOCKS 512
#define CV_BLOCKS 2048
#define ZI_BLOCKS 128

// ---------------- fat kernel: [0,512) GEMM1 ; [512,2560) convert feats ; [2560,2688) zero out ----------------
// GEMM1: Mt[1024][8192] (bf16) = Wt[1024][2048] * compT[8192][2048]^T
__global__ __launch_bounds__(256) void fat_g1_conv_init(
    const unsigned short* __restrict__ Wt, const unsigned short* __restrict__ compT,
    unsigned short* __restrict__ Mt,
    const float* __restrict__ feats, unsigned short* __restrict__ featsB,
    float* __restrict__ out) {
    const int b = blockIdx.x;
    const int t = threadIdx.x;

    if (b < G1_BLOCKS) {
        // ---- GEMM1, M=1024 N=8192 K=2048, nwg=512, row-fast XCD swizzle ----
        const int cpx = G1_BLOCKS >> 3;                 // 64
        const int swz = (b & 7) * cpx + (b >> 3);
        const int row0 = (swz & 7) * BM;                // 8 row tiles
        const int col0 = (swz >> 3) * BN;               // 64 col tiles
        const int Kk = 2048, Nn = 8192;

        __shared__ unsigned short As[BM * BK];
        __shared__ unsigned short Bs[BN * BK];
        const int lane = t & 63, w = t >> 6;
        const int wr = w >> 1, wc = w & 1;
        const int lr = lane & 15, hi = lane >> 4;

        f32x4 acc[4][4];
#pragma unroll
        for (int m = 0; m < 4; ++m)
#pragma unroll
            for (int n = 0; n < 4; ++n) acc[m][n] = (f32x4){0.f, 0.f, 0.f, 0.f};

        const int sr = t >> 3;
        const int sc = (t & 7) * 8;

        for (int k0 = 0; k0 < Kk; k0 += BK) {
#pragma unroll
            for (int i = 0; i < 4; ++i) {
                int r = i * 32 + sr;
                gload_lds16(Wt + (size_t)(row0 + r) * Kk + (k0 + sc), &As[r * BK + sc]);
                gload_lds16(compT + (size_t)(col0 + r) * Kk + (k0 + sc), &Bs[r * BK + sc]);
            }
            __syncthreads();
#pragma unroll
            for (int s = 0; s < 2; ++s) {
                short8 a[4], bb[4];
#pragma unroll
                for (int m = 0; m < 4; ++m)
                    a[m] = *(const short8*)&As[(wr * 64 + m * 16 + lr) * BK + s * 32 + hi * 8];
#pragma unroll
                for (int n = 0; n < 4; ++n)
                    bb[n] = *(const short8*)&Bs[(wc * 64 + n * 16 + lr) * BK + s * 32 + hi * 8];
#pragma unroll
                for (int m = 0; m < 4; ++m)
#pragma unroll
                    for (int n = 0; n < 4; ++n)
                        acc[m][n] = __builtin_amdgcn_mfma_f32_16x16x32_bf16(a[m], bb[n], acc[m][n], 0, 0, 0);
            }
            __syncthreads();
        }
#pragma unroll
        for (int m = 0; m < 4; ++m) {
            int rg = row0 + wr * 64 + m * 16 + hi * 4;
#pragma unroll
            for (int n = 0; n < 4; ++n) {
                int cg = col0 + wc * 64 + n * 16 + lr;
#pragma unroll
                for (int j = 0; j < 4; ++j)
                    Mt[(size_t)(rg + j) * Nn + cg] = f32_to_bf16(acc[m][n][j]);
            }
        }
    } else if (b < G1_BLOCKS + CV_BLOCKS) {
        // ---- convert feats fp32 -> bf16, 64M elements ----
        const int cb = b - G1_BLOCKS;
        const size_t n = (size_t)8192 * 8192;
        size_t i = ((size_t)cb * 256 + t) * 8;
        const size_t stride = (size_t)CV_BLOCKS * 256 * 8;
        for (; i < n; i += stride) {
            f32x4 v0 = *(const f32x4*)(feats + i);
            f32x4 v1 = *(const f32x4*)(feats + i + 4);
            short8 h;
#pragma unroll
            for (int j = 0; j < 4; ++j) h[j] = (short)f32_to_bf16(v0[j]);
#pragma unroll
            for (int j = 0; j < 4; ++j) h[4 + j] = (short)f32_to_bf16(v1[j]);
            *(short8*)(featsB + i) = h;
        }
    } else {
        // ---- zero-init out (8192*1000 f32) ----
        const int zb = b - G1_BLOCKS - CV_BLOCKS;
        const size_t total = (size_t)8192 * 1000;
        size_t i = ((size_t)zb * 256 + t) * 4;
        const size_t stride = (size_t)ZI_BLOCKS * 256 * 4;
        const f32x4 z = (f32x4){0.f, 0.f, 0.f, 0.f};
        for (; i < total; i += stride)
            *(f32x4*)(out + i) = z;
    }
}

// ---------------- GEMM2 split-K=2, atomic accumulate ----------------
// out[8192][1000] += featsB[8192][8192(bf16)] * Mt[1024][8192]^T  (+bias on ks==0)
// grid 1024, XCD-chunked swizzle; decode: col = swz&7, ks = (swz>>3)&1, row = swz>>4
// (16 consecutive swz share one 1MB A row-panel -> L2-resident)
__global__ __launch_bounds__(256) void gemm2_sk2(
    const unsigned short* __restrict__ A, const unsigned short* __restrict__ Bt,
    const float* __restrict__ bias, float* __restrict__ out,
    int M, int N, int K, int Nout) {
    const int nwg = gridDim.x;                  // 1024
    const int cpx = nwg >> 3;
    const int bid = blockIdx.x;
    const int swz = (bid & 7) * cpx + (bid >> 3);
    const int col0 = (swz & 7) * BN;
    const int ks = (swz >> 3) & 1;
    const int row0 = (swz >> 4) * BM;
    const int kbase = ks * (K >> 1);
    const int kend = kbase + (K >> 1);

    __shared__ unsigned short As[BM * BK];
    __shared__ unsigned short Bs[BN * BK];
    const int t = threadIdx.x;
    const int lane = t & 63, w = t >> 6;
    const int wr = w >> 1, wc = w & 1;
    const int lr = lane & 15, hi = lane >> 4;

    f32x4 acc[4][4];
#pragma unroll
    for (int m = 0; m < 4; ++m)
#pragma unroll
        for (int n = 0; n < 4; ++n) acc[m][n] = (f32x4){0.f, 0.f, 0.f, 0.f};

    const int sr = t >> 3;
    const int sc = (t & 7) * 8;

    for (int k0 = kbase; k0 < kend; k0 += BK) {
#pragma unroll
        for (int i = 0; i < 4; ++i) {
            int r = i * 32 + sr;
            gload_lds16(A + (size_t)(row0 + r) * K + (k0 + sc), &As[r * BK + sc]);
            gload_lds16(Bt + (size_t)(col0 + r) * K + (k0 + sc), &Bs[r * BK + sc]);
        }
        __syncthreads();
#pragma unroll
        for (int s = 0; s < 2; ++s) {
            short8 a[4], bb[4];
#pragma unroll
            for (int m = 0; m < 4; ++m)
                a[m] = *(const short8*)&As[(wr * 64 + m * 16 + lr) * BK + s * 32 + hi * 8];
#pragma unroll
            for (int n = 0; n < 4; ++n)
                bb[n] = *(const short8*)&Bs[(wc * 64 + n * 16 + lr) * BK + s * 32 + hi * 8];
#pragma unroll
            for (int m = 0; m < 4; ++m)
#pragma unroll
                for (int n = 0; n < 4; ++n)
                    acc[m][n] = __builtin_amdgcn_mfma_f32_16x16x32_bf16(a[m], bb[n], acc[m][n], 0, 0, 0);
        }
        __syncthreads();
    }
    // epilogue: 2 atomic contributions per element; f32 add is commutative -> deterministic.
#pragma unroll
    for (int m = 0; m < 4; ++m) {
        int rg = row0 + wr * 64 + m * 16 + hi * 4;
#pragma unroll
        for (int n = 0; n < 4; ++n) {
            int cg = col0 + wc * 64 + n * 16 + lr;
            if (cg < Nout) {
                float bv = (ks == 0) ? bias[cg] : 0.f;
#pragma unroll
                for (int j = 0; j < 4; ++j)
                    atomicAdd(&out[(size_t)(rg + j) * Nout + cg], acc[m][n][j] + bv);
            }
        }
    }
}

// ---------------- fallback (small ws): fp32 A reg-staged, 64x128 tile, non-split ----------------
__global__ __launch_bounds__(256) void gemm2_f32a(
    const float* __restrict__ A, const unsigned short* __restrict__ Bt,
    const float* __restrict__ bias, float* __restrict__ out,
    int M, int N, int K, int Nout) {
    const int nwg = gridDim.x;
    const int cpx = nwg >> 3;
    const int bid = blockIdx.x;
    const int swz = (bid & 7) * cpx + (bid >> 3);
    const int ncol = N / 128;
    const int col0 = (swz % ncol) * 128;
    const int row0 = (swz / ncol) * 64;

    __shared__ unsigned short As[64 * 64];
    __shared__ unsigned short Bs[128 * 64];
    const int t = threadIdx.x;
    const int lane = t & 63, w = t >> 6;
    const int wr = w >> 1, wc = w & 1;
    const int lr = lane & 15, hi = lane >> 4;

    f32x4 acc[2][4];
#pragma unroll
    for (int m = 0; m < 2; ++m)
#pragma unroll
        for (int n = 0; n < 4; ++n) acc[m][n] = (f32x4){0.f, 0.f, 0.f, 0.f};

    const int sr = t >> 3;
    const int sc = (t & 7) * 8;

    for (int k0 = 0; k0 < K; k0 += 64) {
#pragma unroll
        for (int i = 0; i < 4; ++i) {
            int r = i * 32 + sr;
            gload_lds16(Bt + (size_t)(col0 + r) * K + (k0 + sc), &Bs[r * 64 + sc]);
        }
#pragma unroll
        for (int i = 0; i < 4; ++i) {
            int e = i * 1024 + t * 4;
            int r = e >> 6, c = e & 63;
            f32x4 v = *(const f32x4*)(A + (size_t)(row0 + r) * K + (k0 + c));
            short4v h;
            h[0] = (short)f32_to_bf16(v[0]);
            h[1] = (short)f32_to_bf16(v[1]);
            h[2] = (short)f32_to_bf16(v[2]);
            h[3] = (short)f32_to_bf16(v[3]);
            *(short4v*)&As[r * 64 + c] = h;
        }
        __syncthreads();
#pragma unroll
        for (int s = 0; s < 2; ++s) {
            short8 a[2], bb[4];
#pragma unroll
            for (int m = 0; m < 2; ++m)
                a[m] = *(const short8*)&As[(wr * 32 + m * 16 + lr) * 64 + s * 32 + hi * 8];
#pragma unroll
            for (int n = 0; n < 4; ++n)
                bb[n] = *(const short8*)&Bs[(wc * 64 + n * 16 + lr) * 64 + s * 32 + hi * 8];
#pragma unroll
            for (int m = 0; m < 2; ++m)
#pragma unroll
                for (int n = 0; n < 4; ++n)
                    acc[m][n] = __builtin_amdgcn_mfma_f32_16x16x32_bf16(a[m], bb[n], acc[m][n], 0, 0, 0);
        }
        __syncthreads();
    }
#pragma unroll
    for (int m = 0; m < 2; ++m) {
        int rg = row0 + wr * 32 + m * 16 + hi * 4;
#pragma unroll
        for (int n = 0; n < 4; ++n) {
            int cg = col0 + wc * 64 + n * 16 + lr;
            if (cg < Nout) {
                float bv = bias[cg];
#pragma unroll
                for (int j = 0; j < 4; ++j)
                    out[(size_t)(rg + j) * Nout + cg] = acc[m][n][j] + bv;
            }
        }
    }
}

extern "C" void kernel_launch(void* const* d_in, const int* in_sizes, int n_in,
                              void* d_out, int out_size, void* d_ws, size_t ws_size,
                              hipStream_t stream) {
    const float* feats = (const float*)d_in[0];   // [8192][8192]
    const float* mean  = (const float*)d_in[1];   // [8192]
    const float* comp  = (const float*)d_in[2];   // [2048][8192]
    const float* W     = (const float*)d_in[3];   // [2048][1000]
    float* out = (float*)d_out;                   // [8192][1000]

    const int N = 8192, D = 8192, Kp = 2048, C = 1000, Cp = 1024;

    char* ws = (char*)d_ws;
    unsigned short* Wt    = (unsigned short*)ws;                  // [Cp][Kp]   4 MB
    size_t off = (size_t)Cp * Kp * 2;
    unsigned short* compT = (unsigned short*)(ws + off);          // [D][Kp]   32 MB
    off += (size_t)D * Kp * 2;
    unsigned short* Mt    = (unsigned short*)(ws + off);          // [Cp][D]   16 MB
    off += (size_t)Cp * D * 2;
    float* bias           = (float*)(ws + off);                   // [Cp]
    off += 4096;
    unsigned short* featsB = (unsigned short*)(ws + off);         // [N][D]   128 MB
    const size_t need_big = off + (size_t)N * D * 2;

    dim3 tb(32, 8);
    transpose_to_bf16<<<dim3(Cp / 32, Kp / 32), tb, 0, stream>>>(W, Wt, Kp, C, Cp);
    transpose_to_bf16<<<dim3(D / 32, Kp / 32), tb, 0, stream>>>(comp, compT, Kp, D, D);

    if (ws_size >= need_big) {
        // GEMM1 (512 blocks) || feats convert (2048) || out zero-init (128)
        fat_g1_conv_init<<<G1_BLOCKS + CV_BLOCKS + ZI_BLOCKS, 256, 0, stream>>>(
            Wt, compT, Mt, feats, featsB, out);
        bias_kernel<<<Cp, 256, 0, stream>>>(mean, Mt, bias, D);
        // split-K=2, 1024 blocks = 4/CU, atomic accumulate into out
        gemm2_sk2<<<2 * (N / BM) * (Cp / BN), 256, 0, stream>>>(featsB, Mt, bias, out, N, Cp, D, C);
    } else {
        // fallback: GEMM1 alone, then fused-convert GEMM2
        fat_g1_conv_init<<<G1_BLOCKS, 256, 0, stream>>>(Wt, compT, Mt, feats, featsB, out);
        bias_kernel<<<Cp, 256, 0, stream>>>(mean, Mt, bias, D);
        gemm2_f32a<<<(N / 64) * (Cp / 128), 256, 0, stream>>>(feats, Mt, bias, out, N, Cp, D, C);
    }
}

// Round 6
// 317.382 us; speedup vs baseline: 1.3918x; 1.3918x over previous
//
#include <hip/hip_runtime.h>
#include <hip/hip_bf16.h>

typedef __attribute__((ext_vector_type(4))) float  f32x4;
typedef __attribute__((ext_vector_type(8))) short  short8;
typedef __attribute__((ext_vector_type(4))) short  short4v;

__device__ __forceinline__ unsigned short f32_to_bf16(float f) {
    union { float f; unsigned u; } v; v.f = f;
    unsigned r = v.u + 0x7FFFu + ((v.u >> 16) & 1u);   // RNE
    return (unsigned short)(r >> 16);
}
__device__ __forceinline__ float bf16_to_f32(unsigned short h) {
    union { unsigned u; float f; } v; v.u = ((unsigned)h) << 16; return v.f;
}
__device__ __forceinline__ void gload_lds16(const void* g, void* l) {
    __builtin_amdgcn_global_load_lds(
        (const __attribute__((address_space(1))) unsigned int*)g,
        (__attribute__((address_space(3))) unsigned int*)l,
        16, 0, 0);
}

// ---------------- transpose + fp32->bf16 convert ----------------
__global__ __launch_bounds__(256) void transpose_to_bf16(
    const float* __restrict__ src, unsigned short* __restrict__ dst,
    int R, int Cin, int Cpad) {
    __shared__ float tile[32][33];
    const int tx = threadIdx.x, ty = threadIdx.y;
    const int c0 = blockIdx.x * 32, r0 = blockIdx.y * 32;
#pragma unroll
    for (int i = 0; i < 4; ++i) {
        int r = r0 + ty + i * 8, c = c0 + tx;
        float v = 0.f;
        if (r < R && c < Cin) v = src[(size_t)r * Cin + c];
        tile[ty + i * 8][tx] = v;
    }
    __syncthreads();
#pragma unroll
    for (int i = 0; i < 4; ++i) {
        int c = c0 + ty + i * 8, r = r0 + tx;
        if (c < Cpad && r < R)
            dst[(size_t)c * R + r] = f32_to_bf16(tile[tx][ty + i * 8]);
    }
}

// ---------------- flat fp32 -> bf16 convert ----------------
__global__ __launch_bounds__(256) void convert_f32_bf16(
    const float* __restrict__ src, unsigned short* __restrict__ dst, size_t n) {
    size_t i = ((size_t)blockIdx.x * 256 + threadIdx.x) * 8;
    const size_t stride = (size_t)gridDim.x * 256 * 8;
    for (; i < n; i += stride) {
        f32x4 v0 = *(const f32x4*)(src + i);
        f32x4 v1 = *(const f32x4*)(src + i + 4);
        short8 h;
#pragma unroll
        for (int j = 0; j < 4; ++j) h[j] = (short)f32_to_bf16(v0[j]);
#pragma unroll
        for (int j = 0; j < 4; ++j) h[4 + j] = (short)f32_to_bf16(v1[j]);
        *(short8*)(dst + i) = h;
    }
}

// ---------------- bias[c] = -sum_d mean[d] * Mt[c][d] ----------------
__global__ __launch_bounds__(256) void bias_kernel(
    const float* __restrict__ mean, const unsigned short* __restrict__ Mt,
    float* __restrict__ bias, int D) {
    const int c = blockIdx.x;
    const unsigned short* row = Mt + (size_t)c * D;
    float s = 0.f;
    for (int d0 = threadIdx.x * 8; d0 < D; d0 += 256 * 8) {
        short4v h0 = *(const short4v*)&row[d0];
        short4v h1 = *(const short4v*)&row[d0 + 4];
        f32x4  m0 = *(const f32x4*)&mean[d0];
        f32x4  m1 = *(const f32x4*)&mean[d0 + 4];
#pragma unroll
        for (int j = 0; j < 4; ++j) {
            s += bf16_to_f32((unsigned short)h0[j]) * m0[j];
            s += bf16_to_f32((unsigned short)h1[j]) * m1[j];
        }
    }
#pragma unroll
    for (int off = 32; off > 0; off >>= 1) s += __shfl_down(s, off);
    __shared__ float red[4];
    const int lane = threadIdx.x & 63, w = threadIdx.x >> 6;
    if (lane == 0) red[w] = s;
    __syncthreads();
    if (threadIdx.x == 0) bias[c] = -(red[0] + red[1] + red[2] + red[3]);
}

// ================= deep-pipelined GEMM: 256x128 tile, BK=64, 512 thr, 3-buf LDS =================
// LDS per buffer: A 256x64 bf16 (32KB) + B 128x64 bf16 (16KB) = 48KB; x3 = 144KB dynamic.
// Swizzle: byte ^= (row&7)<<4 within each 128B row (involution). Staged via pre-swizzled
// global source + linear global_load_lds dest (rule #21); reads apply the same XOR.
#define P_BM 256
#define P_BN 128
#define P_BK 64
#define ABUF 16384   /* elements (256*64) */
#define BBUF 8192    /* elements (128*64) */
#define BUFE 24576   /* per-buffer elements */
#define P_LDS_BYTES (3 * BUFE * 2)

// stage passes [P0,P1) of a region (each pass: 512 threads x 16B, 64 rows of 128B)
template<int P0, int P1>
__device__ __forceinline__ void stage_part(
    const unsigned short* __restrict__ g, int K, int k0,
    unsigned short* l, int tid) {
#pragma unroll
    for (int p = P0; p < P1; ++p) {
        unsigned lin = ((unsigned)p * 512 + (unsigned)tid) * 16u;   // byte offset in region
        unsigned row = lin >> 7;
        unsigned colb = (lin ^ ((row & 7u) << 4)) & 127u;
        gload_lds16((const char*)g + (size_t)row * K * 2 + (size_t)k0 * 2 + colb,
                    (char*)l + lin);
    }
}

__device__ __forceinline__ short8 lfrag(const unsigned short* base, unsigned row, unsigned cb) {
    unsigned lin = row * 128u + cb;
    unsigned b = lin ^ ((row & 7u) << 4);
    return *(const short8*)((const char*)base + b);
}

// MODE 0: C bf16 [M][N] (GEMM1: row0=(bid&3)*256, col0=(bid>>2)*128)
// MODE 1: out f32 [M][Nout] + bias, col guard (GEMM2: col0=(bid&7)*128, row0=(bid>>3)*256)
template<int MODE>
__global__ __launch_bounds__(512) void gemm8p(
    const unsigned short* __restrict__ A, const unsigned short* __restrict__ Bt,
    const float* __restrict__ bias, void* __restrict__ Cptr,
    int M, int N, int K, int Nout) {
    extern __shared__ unsigned short lds[];
    const int bid = blockIdx.x;
    int row0, col0;
    if (MODE == 0) { row0 = (bid & 3) * P_BM; col0 = (bid >> 2) * P_BN; }
    else           { col0 = (bid & 7) * P_BN; row0 = (bid >> 3) * P_BM; }
    const int tid = threadIdx.x;
    const int w = tid >> 6, lane = tid & 63;
    const int wm = w >> 1, wn = w & 1;
    const int lr = lane & 15, hi = lane >> 4;
    const int arow = wm * 64 + lr;
    const int brow = wn * 64 + lr;

    const unsigned short* Ag = A + (size_t)row0 * K;
    const unsigned short* Bg = Bt + (size_t)col0 * K;

    f32x4 acc[4][4];
#pragma unroll
    for (int m = 0; m < 4; ++m)
#pragma unroll
        for (int n = 0; n < 4; ++n) acc[m][n] = (f32x4){0.f, 0.f, 0.f, 0.f};

    const int NT = K / P_BK;
    // prologue: stage tile 0 -> buf0, tile 1 -> buf1  (12 loads in flight)
    stage_part<0, 4>(Ag, K, 0, lds, tid);
    stage_part<0, 2>(Bg, K, 0, lds + ABUF, tid);
    stage_part<0, 4>(Ag, K, P_BK, lds + BUFE, tid);
    stage_part<0, 2>(Bg, K, P_BK, lds + BUFE + ABUF, tid);

    for (int t = 0; t < NT; ++t) {
        // wait tile t landed: 6 loads (tile t+1) may stay in flight. Never 0 mid-loop (T4).
        if (t + 1 < NT) asm volatile("s_waitcnt vmcnt(6)" ::: "memory");
        else            asm volatile("s_waitcnt vmcnt(0)" ::: "memory");
        __builtin_amdgcn_sched_barrier(0);
        __builtin_amdgcn_s_barrier();      // all waves done with tile t-1 -> buf[(t+2)%3] free
        __builtin_amdgcn_sched_barrier(0);

        unsigned short* buf = lds + (t % 3) * BUFE;
        const unsigned short* As = buf;
        const unsigned short* Bs = buf + ABUF;
        unsigned short* nbuf = lds + ((t + 2) % 3) * BUFE;
        const bool st = (t + 2 < NT);
        const int k2 = (t + 2) * P_BK;

        if (st) stage_part<0, 2>(Ag, K, k2, nbuf, tid);

        short8 bf[4][2];
#pragma unroll
        for (int n = 0; n < 4; ++n)
#pragma unroll
            for (int s = 0; s < 2; ++s)
                bf[n][s] = lfrag(Bs, brow + n * 16, s * 64 + hi * 16);
        short8 af0[2][2];
#pragma unroll
        for (int m = 0; m < 2; ++m)
#pragma unroll
            for (int s = 0; s < 2; ++s)
                af0[m][s] = lfrag(As, arow + m * 16, s * 64 + hi * 16);

        if (st) stage_part<2, 4>(Ag, K, k2, nbuf, tid);

        __builtin_amdgcn_s_setprio(1);
#pragma unroll
        for (int m = 0; m < 2; ++m)
#pragma unroll
            for (int n = 0; n < 4; ++n)
#pragma unroll
                for (int s = 0; s < 2; ++s)
                    acc[m][n] = __builtin_amdgcn_mfma_f32_16x16x32_bf16(af0[m][s], bf[n][s], acc[m][n], 0, 0, 0);
        __builtin_amdgcn_s_setprio(0);

        short8 af1[2][2];
#pragma unroll
        for (int m = 0; m < 2; ++m)
#pragma unroll
            for (int s = 0; s < 2; ++s)
                af1[m][s] = lfrag(As, arow + 32 + m * 16, s * 64 + hi * 16);

        if (st) stage_part<0, 2>(Bg, K, k2, nbuf + ABUF, tid);

        __builtin_amdgcn_s_setprio(1);
#pragma unroll
        for (int m = 0; m < 2; ++m)
#pragma unroll
            for (int n = 0; n < 4; ++n)
#pragma unroll
                for (int s = 0; s < 2; ++s)
                    acc[2 + m][n] = __builtin_amdgcn_mfma_f32_16x16x32_bf16(af1[m][s], bf[n][s], acc[2 + m][n], 0, 0, 0);
        __builtin_amdgcn_s_setprio(0);
    }

    if (MODE == 0) {
        unsigned short* C = (unsigned short*)Cptr;
#pragma unroll
        for (int m = 0; m < 4; ++m) {
            int rg = row0 + wm * 64 + m * 16 + hi * 4;
#pragma unroll
            for (int n = 0; n < 4; ++n) {
                int cg = col0 + wn * 64 + n * 16 + lr;
#pragma unroll
                for (int j = 0; j < 4; ++j)
                    C[(size_t)(rg + j) * N + cg] = f32_to_bf16(acc[m][n][j]);
            }
        }
    } else {
        float* C = (float*)Cptr;
#pragma unroll
        for (int m = 0; m < 4; ++m) {
            int rg = row0 + wm * 64 + m * 16 + hi * 4;
#pragma unroll
            for (int n = 0; n < 4; ++n) {
                int cg = col0 + wn * 64 + n * 16 + lr;
                if (cg < Nout) {
                    float bv = bias[cg];
#pragma unroll
                    for (int j = 0; j < 4; ++j)
                        C[(size_t)(rg + j) * Nout + cg] = acc[m][n][j] + bv;
                }
            }
        }
    }
}

// ---------------- fallback (small ws): fp32 A reg-staged, 64x128 tile ----------------
__global__ __launch_bounds__(256) void gemm2_f32a(
    const float* __restrict__ A, const unsigned short* __restrict__ Bt,
    const float* __restrict__ bias, float* __restrict__ out,
    int M, int N, int K, int Nout) {
    const int nwg = gridDim.x;
    const int cpx = nwg >> 3;
    const int bid = blockIdx.x;
    const int swz = (bid & 7) * cpx + (bid >> 3);
    const int ncol = N / 128;
    const int col0 = (swz % ncol) * 128;
    const int row0 = (swz / ncol) * 64;

    __shared__ unsigned short As[64 * 64];
    __shared__ unsigned short Bs[128 * 64];
    const int t = threadIdx.x;
    const int lane = t & 63, w = t >> 6;
    const int wr = w >> 1, wc = w & 1;
    const int lr = lane & 15, hi = lane >> 4;

    f32x4 acc[2][4];
#pragma unroll
    for (int m = 0; m < 2; ++m)
#pragma unroll
        for (int n = 0; n < 4; ++n) acc[m][n] = (f32x4){0.f, 0.f, 0.f, 0.f};

    const int sr = t >> 3;
    const int sc = (t & 7) * 8;

    for (int k0 = 0; k0 < K; k0 += 64) {
#pragma unroll
        for (int i = 0; i < 4; ++i) {
            int r = i * 32 + sr;
            gload_lds16(Bt + (size_t)(col0 + r) * K + (k0 + sc), &Bs[r * 64 + sc]);
        }
#pragma unroll
        for (int i = 0; i < 4; ++i) {
            int e = i * 1024 + t * 4;
            int r = e >> 6, c = e & 63;
            f32x4 v = *(const f32x4*)(A + (size_t)(row0 + r) * K + (k0 + c));
            short4v h;
            h[0] = (short)f32_to_bf16(v[0]);
            h[1] = (short)f32_to_bf16(v[1]);
            h[2] = (short)f32_to_bf16(v[2]);
            h[3] = (short)f32_to_bf16(v[3]);
            *(short4v*)&As[r * 64 + c] = h;
        }
        __syncthreads();
#pragma unroll
        for (int s = 0; s < 2; ++s) {
            short8 a[2], bb[4];
#pragma unroll
            for (int m = 0; m < 2; ++m)
                a[m] = *(const short8*)&As[(wr * 32 + m * 16 + lr) * 64 + s * 32 + hi * 8];
#pragma unroll
            for (int n = 0; n < 4; ++n)
                bb[n] = *(const short8*)&Bs[(wc * 64 + n * 16 + lr) * 64 + s * 32 + hi * 8];
#pragma unroll
            for (int m = 0; m < 2; ++m)
#pragma unroll
                for (int n = 0; n < 4; ++n)
                    acc[m][n] = __builtin_amdgcn_mfma_f32_16x16x32_bf16(a[m], bb[n], acc[m][n], 0, 0, 0);
        }
        __syncthreads();
    }
#pragma unroll
    for (int m = 0; m < 2; ++m) {
        int rg = row0 + wr * 32 + m * 16 + hi * 4;
#pragma unroll
        for (int n = 0; n < 4; ++n) {
            int cg = col0 + wc * 64 + n * 16 + lr;
            if (cg < Nout) {
                float bv = bias[cg];
#pragma unroll
                for (int j = 0; j < 4; ++j)
                    out[(size_t)(rg + j) * Nout + cg] = acc[m][n][j] + bv;
            }
        }
    }
}

extern "C" void kernel_launch(void* const* d_in, const int* in_sizes, int n_in,
                              void* d_out, int out_size, void* d_ws, size_t ws_size,
                              hipStream_t stream) {
    const float* feats = (const float*)d_in[0];   // [8192][8192]
    const float* mean  = (const float*)d_in[1];   // [8192]
    const float* comp  = (const float*)d_in[2];   // [2048][8192]
    const float* W     = (const float*)d_in[3];   // [2048][1000]
    float* out = (float*)d_out;                   // [8192][1000]

    const int N = 8192, D = 8192, Kp = 2048, C = 1000, Cp = 1024;

    char* ws = (char*)d_ws;
    unsigned short* Wt    = (unsigned short*)ws;                  // [Cp][Kp]   4 MB
    size_t off = (size_t)Cp * Kp * 2;
    unsigned short* compT = (unsigned short*)(ws + off);          // [D][Kp]   32 MB
    off += (size_t)D * Kp * 2;
    unsigned short* Mt    = (unsigned short*)(ws + off);          // [Cp][D]   16 MB
    off += (size_t)Cp * D * 2;
    float* bias           = (float*)(ws + off);                   // [Cp]
    off += 4096;
    unsigned short* featsB = (unsigned short*)(ws + off);         // [N][D]   128 MB
    const size_t need_big = off + (size_t)N * D * 2;

    dim3 tb(32, 8);
    transpose_to_bf16<<<dim3(Cp / 32, Kp / 32), tb, 0, stream>>>(W, Wt, Kp, C, Cp);
    transpose_to_bf16<<<dim3(D / 32, Kp / 32), tb, 0, stream>>>(comp, compT, Kp, D, D);

    hipFuncSetAttribute(reinterpret_cast<const void*>(gemm8p<0>),
                        hipFuncAttributeMaxDynamicSharedMemorySize, P_LDS_BYTES);
    hipFuncSetAttribute(reinterpret_cast<const void*>(gemm8p<1>),
                        hipFuncAttributeMaxDynamicSharedMemorySize, P_LDS_BYTES);

    // GEMM1: Mt[1024][8192] = Wt[1024][2048] @ compT[8192][2048]^T ; grid 4x64 = 256 = 1/CU
    gemm8p<0><<<(Cp / P_BM) * (D / P_BN), 512, P_LDS_BYTES, stream>>>(
        Wt, compT, nullptr, Mt, Cp, D, Kp, D);
    bias_kernel<<<Cp, 256, 0, stream>>>(mean, Mt, bias, D);

    if (ws_size >= need_big) {
        convert_f32_bf16<<<2048, 256, 0, stream>>>(feats, featsB, (size_t)N * D);
        // GEMM2: out[8192][1000] = featsB @ Mt^T + bias ; grid 32x8 = 256 = 1/CU
        gemm8p<1><<<(N / P_BM) * (Cp / P_BN), 512, P_LDS_BYTES, stream>>>(
            featsB, Mt, bias, out, N, Cp, D, C);
    } else {
        gemm2_f32a<<<(N / 64) * (Cp / 128), 256, 0, stream>>>(feats, Mt, bias, out, N, Cp, D, C);
    }
}

// Round 7
// 278.468 us; speedup vs baseline: 1.5863x; 1.1397x over previous
//
#include <hip/hip_runtime.h>
#include <hip/hip_bf16.h>

typedef __attribute__((ext_vector_type(4))) float  f32x4;
typedef __attribute__((ext_vector_type(8))) short  short8;
typedef __attribute__((ext_vector_type(4))) short  short4v;

__device__ __forceinline__ unsigned short f32_to_bf16(float f) {
    union { float f; unsigned u; } v; v.f = f;
    unsigned r = v.u + 0x7FFFu + ((v.u >> 16) & 1u);   // RNE
    return (unsigned short)(r >> 16);
}
__device__ __forceinline__ float bf16_to_f32(unsigned short h) {
    union { unsigned u; float f; } v; v.u = ((unsigned)h) << 16; return v.f;
}
__device__ __forceinline__ void gload_lds16(const void* g, void* l) {
    __builtin_amdgcn_global_load_lds(
        (const __attribute__((address_space(1))) unsigned int*)g,
        (__attribute__((address_space(3))) unsigned int*)l,
        16, 0, 0);
}

// ---------------- transpose + fp32->bf16 convert ----------------
__global__ __launch_bounds__(256) void transpose_to_bf16(
    const float* __restrict__ src, unsigned short* __restrict__ dst,
    int R, int Cin, int Cpad) {
    __shared__ float tile[32][33];
    const int tx = threadIdx.x, ty = threadIdx.y;
    const int c0 = blockIdx.x * 32, r0 = blockIdx.y * 32;
#pragma unroll
    for (int i = 0; i < 4; ++i) {
        int r = r0 + ty + i * 8, c = c0 + tx;
        float v = 0.f;
        if (r < R && c < Cin) v = src[(size_t)r * Cin + c];
        tile[ty + i * 8][tx] = v;
    }
    __syncthreads();
#pragma unroll
    for (int i = 0; i < 4; ++i) {
        int c = c0 + ty + i * 8, r = r0 + tx;
        if (c < Cpad && r < R)
            dst[(size_t)c * R + r] = f32_to_bf16(tile[tx][ty + i * 8]);
    }
}

// ---------------- flat fp32 -> bf16 convert ----------------
__global__ __launch_bounds__(256) void convert_f32_bf16(
    const float* __restrict__ src, unsigned short* __restrict__ dst, size_t n) {
    size_t i = ((size_t)blockIdx.x * 256 + threadIdx.x) * 8;
    const size_t stride = (size_t)gridDim.x * 256 * 8;
    for (; i < n; i += stride) {
        f32x4 v0 = *(const f32x4*)(src + i);
        f32x4 v1 = *(const f32x4*)(src + i + 4);
        short8 h;
#pragma unroll
        for (int j = 0; j < 4; ++j) h[j] = (short)f32_to_bf16(v0[j]);
#pragma unroll
        for (int j = 0; j < 4; ++j) h[4 + j] = (short)f32_to_bf16(v1[j]);
        *(short8*)(dst + i) = h;
    }
}

// ---------------- bias[c] = -sum_d mean[d] * Mt[c][d] ----------------
__global__ __launch_bounds__(256) void bias_kernel(
    const float* __restrict__ mean, const unsigned short* __restrict__ Mt,
    float* __restrict__ bias, int D) {
    const int c = blockIdx.x;
    const unsigned short* row = Mt + (size_t)c * D;
    float s = 0.f;
    for (int d0 = threadIdx.x * 8; d0 < D; d0 += 256 * 8) {
        short4v h0 = *(const short4v*)&row[d0];
        short4v h1 = *(const short4v*)&row[d0 + 4];
        f32x4  m0 = *(const f32x4*)&mean[d0];
        f32x4  m1 = *(const f32x4*)&mean[d0 + 4];
#pragma unroll
        for (int j = 0; j < 4; ++j) {
            s += bf16_to_f32((unsigned short)h0[j]) * m0[j];
            s += bf16_to_f32((unsigned short)h1[j]) * m1[j];
        }
    }
#pragma unroll
    for (int off = 32; off > 0; off >>= 1) s += __shfl_down(s, off);
    __shared__ float red[4];
    const int lane = threadIdx.x & 63, w = threadIdx.x >> 6;
    if (lane == 0) red[w] = s;
    __syncthreads();
    if (threadIdx.x == 0) bias[c] = -(red[0] + red[1] + red[2] + red[3]);
}

// ================= deep-pipelined GEMM: 256x128 tile, BK=64, 512 thr, 3-buf LDS =================
// LDS per buffer: A 256x64 bf16 (32KB) + B 128x64 bf16 (16KB) = 48KB; x3 = 144KB dynamic.
// Swizzle: byte ^= (row&7)<<4 within each 128B row (involution). Staged via pre-swizzled
// global source + linear global_load_lds dest (rule #21); reads apply the same XOR.
#define P_BM 256
#define P_BN 128
#define P_BK 64
#define ABUF 16384   /* elements (256*64) */
#define BBUF 8192    /* elements (128*64) */
#define BUFE 24576   /* per-buffer elements */
#define P_LDS_BYTES (3 * BUFE * 2)

// stage passes [P0,P1) of a region (each pass: 512 threads x 16B, 64 rows of 128B)
template<int P0, int P1>
__device__ __forceinline__ void stage_part(
    const unsigned short* __restrict__ g, int K, int k0,
    unsigned short* l, int tid) {
#pragma unroll
    for (int p = P0; p < P1; ++p) {
        unsigned lin = ((unsigned)p * 512 + (unsigned)tid) * 16u;   // byte offset in region
        unsigned row = lin >> 7;
        unsigned colb = (lin ^ ((row & 7u) << 4)) & 127u;
        gload_lds16((const char*)g + (size_t)row * K * 2 + (size_t)k0 * 2 + colb,
                    (char*)l + lin);
    }
}

__device__ __forceinline__ short8 lfrag(const unsigned short* base, unsigned row, unsigned cb) {
    unsigned lin = row * 128u + cb;
    unsigned b = lin ^ ((row & 7u) << 4);
    return *(const short8*)((const char*)base + b);
}

// Chunked XCD decode (blocks land on XCD bid%8; give each XCD a contiguous rectangle):
// MODE 0 (GEMM1, 4 rows x 64 cols): XCD x -> col panels [8x,8x+8) x all 4 rows.
// MODE 1 (GEMM2, 32 rows x 8 cols): XCD x -> row panels [4x,4x+4) x all 8 cols.
template<int MODE>
__global__ __launch_bounds__(512) void gemm8p(
    const unsigned short* __restrict__ A, const unsigned short* __restrict__ Bt,
    const float* __restrict__ bias, void* __restrict__ Cptr,
    int M, int N, int K, int Nout) {
    extern __shared__ unsigned short lds[];
    const int bid = blockIdx.x;
    const int x = bid & 7, i = bid >> 3;
    int row0, col0;
    if (MODE == 0) { col0 = (x * 8 + (i >> 2)) * P_BN; row0 = (i & 3) * P_BM; }
    else           { row0 = (x * 4 + (i >> 3)) * P_BM; col0 = (i & 7) * P_BN; }
    const int tid = threadIdx.x;
    const int w = tid >> 6, lane = tid & 63;
    const int wm = w >> 1, wn = w & 1;
    const int lr = lane & 15, hi = lane >> 4;
    const int arow = wm * 64 + lr;
    const int brow = wn * 64 + lr;

    const unsigned short* Ag = A + (size_t)row0 * K;
    const unsigned short* Bg = Bt + (size_t)col0 * K;

    f32x4 acc[4][4];
#pragma unroll
    for (int m = 0; m < 4; ++m)
#pragma unroll
        for (int n = 0; n < 4; ++n) acc[m][n] = (f32x4){0.f, 0.f, 0.f, 0.f};

    const int NT = K / P_BK;
    // prologue: stage tile 0 -> buf0, tile 1 -> buf1  (12 loads in flight)
    stage_part<0, 4>(Ag, K, 0, lds, tid);
    stage_part<0, 2>(Bg, K, 0, lds + ABUF, tid);
    stage_part<0, 4>(Ag, K, P_BK, lds + BUFE, tid);
    stage_part<0, 2>(Bg, K, P_BK, lds + BUFE + ABUF, tid);

    for (int t = 0; t < NT; ++t) {
        // wait tile t landed: 6 loads (tile t+1) may stay in flight. Never 0 mid-loop (T4).
        if (t + 1 < NT) asm volatile("s_waitcnt vmcnt(6)" ::: "memory");
        else            asm volatile("s_waitcnt vmcnt(0)" ::: "memory");
        __builtin_amdgcn_sched_barrier(0);
        __builtin_amdgcn_s_barrier();      // all waves done with tile t-1 -> buf[(t+2)%3] free
        __builtin_amdgcn_sched_barrier(0);

        unsigned short* buf = lds + (t % 3) * BUFE;
        const unsigned short* As = buf;
        const unsigned short* Bs = buf + ABUF;
        unsigned short* nbuf = lds + ((t + 2) % 3) * BUFE;
        const bool st = (t + 2 < NT);
        const int k2 = (t + 2) * P_BK;

        if (st) stage_part<0, 2>(Ag, K, k2, nbuf, tid);

        short8 bf[4][2];
#pragma unroll
        for (int n = 0; n < 4; ++n)
#pragma unroll
            for (int s = 0; s < 2; ++s)
                bf[n][s] = lfrag(Bs, brow + n * 16, s * 64 + hi * 16);
        short8 af0[2][2];
#pragma unroll
        for (int m = 0; m < 2; ++m)
#pragma unroll
            for (int s = 0; s < 2; ++s)
                af0[m][s] = lfrag(As, arow + m * 16, s * 64 + hi * 16);

        if (st) stage_part<2, 4>(Ag, K, k2, nbuf, tid);

        __builtin_amdgcn_s_setprio(1);
#pragma unroll
        for (int m = 0; m < 2; ++m)
#pragma unroll
            for (int n = 0; n < 4; ++n)
#pragma unroll
                for (int s = 0; s < 2; ++s)
                    acc[m][n] = __builtin_amdgcn_mfma_f32_16x16x32_bf16(af0[m][s], bf[n][s], acc[m][n], 0, 0, 0);
        __builtin_amdgcn_s_setprio(0);

        short8 af1[2][2];
#pragma unroll
        for (int m = 0; m < 2; ++m)
#pragma unroll
            for (int s = 0; s < 2; ++s)
                af1[m][s] = lfrag(As, arow + 32 + m * 16, s * 64 + hi * 16);

        if (st) stage_part<0, 2>(Bg, K, k2, nbuf + ABUF, tid);

        __builtin_amdgcn_s_setprio(1);
#pragma unroll
        for (int m = 0; m < 2; ++m)
#pragma unroll
            for (int n = 0; n < 4; ++n)
#pragma unroll
                for (int s = 0; s < 2; ++s)
                    acc[2 + m][n] = __builtin_amdgcn_mfma_f32_16x16x32_bf16(af1[m][s], bf[n][s], acc[2 + m][n], 0, 0, 0);
        __builtin_amdgcn_s_setprio(0);
    }

    if (MODE == 0) {
        unsigned short* C = (unsigned short*)Cptr;
#pragma unroll
        for (int m = 0; m < 4; ++m) {
            int rg = row0 + wm * 64 + m * 16 + hi * 4;
#pragma unroll
            for (int n = 0; n < 4; ++n) {
                int cg = col0 + wn * 64 + n * 16 + lr;
#pragma unroll
                for (int j = 0; j < 4; ++j)
                    C[(size_t)(rg + j) * N + cg] = f32_to_bf16(acc[m][n][j]);
            }
        }
    } else {
        float* C = (float*)Cptr;
#pragma unroll
        for (int m = 0; m < 4; ++m) {
            int rg = row0 + wm * 64 + m * 16 + hi * 4;
#pragma unroll
            for (int n = 0; n < 4; ++n) {
                int cg = col0 + wn * 64 + n * 16 + lr;
                if (cg < Nout) {
                    float bv = bias[cg];
#pragma unroll
                    for (int j = 0; j < 4; ++j)
                        C[(size_t)(rg + j) * Nout + cg] = acc[m][n][j] + bv;
                }
            }
        }
    }
}

// ---------------- fallback (small ws): fp32 A reg-staged, 64x128 tile ----------------
__global__ __launch_bounds__(256) void gemm2_f32a(
    const float* __restrict__ A, const unsigned short* __restrict__ Bt,
    const float* __restrict__ bias, float* __restrict__ out,
    int M, int N, int K, int Nout) {
    const int nwg = gridDim.x;
    const int cpx = nwg >> 3;
    const int bid = blockIdx.x;
    const int swz = (bid & 7) * cpx + (bid >> 3);
    const int ncol = N / 128;
    const int col0 = (swz % ncol) * 128;
    const int row0 = (swz / ncol) * 64;

    __shared__ unsigned short As[64 * 64];
    __shared__ unsigned short Bs[128 * 64];
    const int t = threadIdx.x;
    const int lane = t & 63, w = t >> 6;
    const int wr = w >> 1, wc = w & 1;
    const int lr = lane & 15, hi = lane >> 4;

    f32x4 acc[2][4];
#pragma unroll
    for (int m = 0; m < 2; ++m)
#pragma unroll
        for (int n = 0; n < 4; ++n) acc[m][n] = (f32x4){0.f, 0.f, 0.f, 0.f};

    const int sr = t >> 3;
    const int sc = (t & 7) * 8;

    for (int k0 = 0; k0 < K; k0 += 64) {
#pragma unroll
        for (int i = 0; i < 4; ++i) {
            int r = i * 32 + sr;
            gload_lds16(Bt + (size_t)(col0 + r) * K + (k0 + sc), &Bs[r * 64 + sc]);
        }
#pragma unroll
        for (int i = 0; i < 4; ++i) {
            int e = i * 1024 + t * 4;
            int r = e >> 6, c = e & 63;
            f32x4 v = *(const f32x4*)(A + (size_t)(row0 + r) * K + (k0 + c));
            short4v h;
            h[0] = (short)f32_to_bf16(v[0]);
            h[1] = (short)f32_to_bf16(v[1]);
            h[2] = (short)f32_to_bf16(v[2]);
            h[3] = (short)f32_to_bf16(v[3]);
            *(short4v*)&As[r * 64 + c] = h;
        }
        __syncthreads();
#pragma unroll
        for (int s = 0; s < 2; ++s) {
            short8 a[2], bb[4];
#pragma unroll
            for (int m = 0; m < 2; ++m)
                a[m] = *(const short8*)&As[(wr * 32 + m * 16 + lr) * 64 + s * 32 + hi * 8];
#pragma unroll
            for (int n = 0; n < 4; ++n)
                bb[n] = *(const short8*)&Bs[(wc * 64 + n * 16 + lr) * 64 + s * 32 + hi * 8];
#pragma unroll
            for (int m = 0; m < 2; ++m)
#pragma unroll
                for (int n = 0; n < 4; ++n)
                    acc[m][n] = __builtin_amdgcn_mfma_f32_16x16x32_bf16(a[m], bb[n], acc[m][n], 0, 0, 0);
        }
        __syncthreads();
    }
#pragma unroll
    for (int m = 0; m < 2; ++m) {
        int rg = row0 + wr * 32 + m * 16 + hi * 4;
#pragma unroll
        for (int n = 0; n < 4; ++n) {
            int cg = col0 + wc * 64 + n * 16 + lr;
            if (cg < Nout) {
                float bv = bias[cg];
#pragma unroll
                for (int j = 0; j < 4; ++j)
                    out[(size_t)(rg + j) * Nout + cg] = acc[m][n][j] + bv;
            }
        }
    }
}

extern "C" void kernel_launch(void* const* d_in, const int* in_sizes, int n_in,
                              void* d_out, int out_size, void* d_ws, size_t ws_size,
                              hipStream_t stream) {
    const float* feats = (const float*)d_in[0];   // [8192][8192]
    const float* mean  = (const float*)d_in[1];   // [8192]
    const float* comp  = (const float*)d_in[2];   // [2048][8192]
    const float* W     = (const float*)d_in[3];   // [2048][1000]
    float* out = (float*)d_out;                   // [8192][1000]

    const int N = 8192, D = 8192, Kp = 2048, C = 1000, Cp = 1024;

    char* ws = (char*)d_ws;
    unsigned short* Wt    = (unsigned short*)ws;                  // [Cp][Kp]   4 MB
    size_t off = (size_t)Cp * Kp * 2;
    unsigned short* compT = (unsigned short*)(ws + off);          // [D][Kp]   32 MB
    off += (size_t)D * Kp * 2;
    unsigned short* Mt    = (unsigned short*)(ws + off);          // [Cp][D]   16 MB
    off += (size_t)Cp * D * 2;
    float* bias           = (float*)(ws + off);                   // [Cp]
    off += 4096;
    unsigned short* featsB = (unsigned short*)(ws + off);         // [N][D]   128 MB
    const size_t need_big = off + (size_t)N * D * 2;

    dim3 tb(32, 8);
    transpose_to_bf16<<<dim3(Cp / 32, Kp / 32), tb, 0, stream>>>(W, Wt, Kp, C, Cp);
    transpose_to_bf16<<<dim3(D / 32, Kp / 32), tb, 0, stream>>>(comp, compT, Kp, D, D);

    hipFuncSetAttribute(reinterpret_cast<const void*>(gemm8p<0>),
                        hipFuncAttributeMaxDynamicSharedMemorySize, P_LDS_BYTES);
    hipFuncSetAttribute(reinterpret_cast<const void*>(gemm8p<1>),
                        hipFuncAttributeMaxDynamicSharedMemorySize, P_LDS_BYTES);

    // GEMM1: Mt[1024][8192] = Wt[1024][2048] @ compT[8192][2048]^T ; grid 4x64 = 256 = 1/CU
    gemm8p<0><<<(Cp / P_BM) * (D / P_BN), 512, P_LDS_BYTES, stream>>>(
        Wt, compT, nullptr, Mt, Cp, D, Kp, D);
    bias_kernel<<<Cp, 256, 0, stream>>>(mean, Mt, bias, D);

    if (ws_size >= need_big) {
        convert_f32_bf16<<<2048, 256, 0, stream>>>(feats, featsB, (size_t)N * D);
        // GEMM2: out[8192][1000] = featsB @ Mt^T + bias ; grid 32x8 = 256 = 1/CU
        gemm8p<1><<<(N / P_BM) * (Cp / P_BN), 512, P_LDS_BYTES, stream>>>(
            featsB, Mt, bias, out, N, Cp, D, C);
    } else {
        gemm2_f32a<<<(N / 64) * (Cp / 128), 256, 0, stream>>>(feats, Mt, bias, out, N, Cp, D, C);
    }
}